// Round 5
// baseline (305.783 us; speedup 1.0000x reference)
//
#include <hip/hip_runtime.h>
#include <math.h>

// Problem constants (B, N, H, DM) = (2, 128, 2, 512), DK = 256
#define BB 2
#define NN 128
#define HH 2
#define DMM 512
#define DKK 256

typedef unsigned short u16;
typedef unsigned int u32;

// ---------------------------------------------------------------------------
// K1: fused projections (fp32 in, fp32 out to ws).
//   Q = query@Wq+bq, K = key@Wk+bk, V = value@Wv+bv   ((256,512)@(512,512))
//   BX = boxes@Wbox+bbox                              ((256,512)@(512,256))
// Thread computes 8 consecutive output cols; float4 loads for A and W.
// Grid: 64+64+64+32 = 224 blocks of 256.
// ---------------------------------------------------------------------------
__global__ __launch_bounds__(256) void proj_kernel(
    const float* __restrict__ q_in, const float* __restrict__ k_in,
    const float* __restrict__ v_in, const float* __restrict__ bx_in,
    const float* __restrict__ Wq, const float* __restrict__ bq,
    const float* __restrict__ Wk, const float* __restrict__ bk,
    const float* __restrict__ Wv, const float* __restrict__ bv,
    const float* __restrict__ Wb, const float* __restrict__ bb,
    float* __restrict__ Q, float* __restrict__ K,
    float* __restrict__ V, float* __restrict__ BX)
{
    int blk = blockIdx.x;
    const float *A, *W, *bias;
    float* out;
    int cols, base;
    if (blk < 64)       { A = q_in;  W = Wq; bias = bq; out = Q;  cols = 512; base = 0;   }
    else if (blk < 128) { A = k_in;  W = Wk; bias = bk; out = K;  cols = 512; base = 64;  }
    else if (blk < 192) { A = v_in;  W = Wv; bias = bv; out = V;  cols = 512; base = 128; }
    else                { A = bx_in; W = Wb; bias = bb; out = BX; cols = 256; base = 192; }

    int gid = (blk - base) * 256 + threadIdx.x;
    int chunks = cols >> 3;                 // chunks of 8 cols per row
    int row = gid / chunks;                 // 0..255
    int o0  = (gid % chunks) * 8;

    const float4* a4 = (const float4*)(A + row * DMM);
    float acc[8];
#pragma unroll
    for (int j = 0; j < 8; j++) acc[j] = bias[o0 + j];

    for (int k4 = 0; k4 < DMM / 4; k4++) {
        float4 av = a4[k4];
        int kk = k4 * 4;
#pragma unroll
        for (int s = 0; s < 4; s++) {
            float a = (s == 0) ? av.x : (s == 1) ? av.y : (s == 2) ? av.z : av.w;
            const float4 w0 = *(const float4*)(W + (kk + s) * cols + o0);
            const float4 w1 = *(const float4*)(W + (kk + s) * cols + o0 + 4);
            acc[0] += a * w0.x; acc[1] += a * w0.y;
            acc[2] += a * w0.z; acc[3] += a * w0.w;
            acc[4] += a * w1.x; acc[5] += a * w1.y;
            acc[6] += a * w1.z; acc[7] += a * w1.w;
        }
    }
    float* orow = out + row * cols + o0;
#pragma unroll
    for (int j = 0; j < 8; j++) orow[j] = acc[j];
}

// ---------------------------------------------------------------------------
// K2: per-(b,h) stats + softmax.
// Row-i scores (after dropping the row-constant softmax shift) are:
//   m != i :  e_m = scale*(c_m - t_m)
//   m == i :  d_i = scale*(g_i - a_i)
// with t=q.k, a=bx.k, c=q.bx, g=bx.bx over DK.
// attn written fp32 directly into d_out's second output region; K4 re-reads.
// Grid: 4 blocks (b*H+h) of 128 threads.
// ---------------------------------------------------------------------------
__global__ __launch_bounds__(128) void attn_kernel(
    const float* __restrict__ Q, const float* __restrict__ K,
    const float* __restrict__ BX,
    float* __restrict__ attn_out)
{
    int bh = blockIdx.x;          // 0..3
    int b = bh >> 1, h = bh & 1;
    __shared__ float sE[NN], sD[NN];
    int tid = threadIdx.x;        // 0..127

    {   // phase 1: per-token dots
        int j = tid;
        const float* qp = Q + (b * NN + j) * DMM + h * DKK;
        const float* kp = K + (b * NN + j) * DMM + h * DKK;
        const float* xp = BX + (b * NN + j) * DKK;
        float t = 0.f, a = 0.f, c = 0.f, g = 0.f;
        for (int ci = 0; ci < DKK; ci++) {
            float qv = qp[ci], kv = kp[ci], xv = xp[ci];
            t += qv * kv; a += xv * kv; c += qv * xv; g += xv * xv;
        }
        const float scale = 1.0f / sqrtf((float)(NN * DKK));
        sE[j] = scale * (c - t);
        sD[j] = scale * (g - a);
    }
    __syncthreads();

    // phase 2: one softmax row per thread
    int i = tid;
    float di = sD[i];
    float mx = di;
    for (int m = 0; m < NN; m++) {
        float sc = (m == i) ? di : sE[m];
        mx = fmaxf(mx, sc);
    }
    float sum = 0.f;
    for (int m = 0; m < NN; m++) {
        float sc = (m == i) ? di : sE[m];
        sum += __expf(sc - mx);
    }
    float inv = 1.0f / sum;
    float* arow = attn_out + (bh * NN + i) * NN;
    for (int m = 0; m < NN; m++) {
        float sc = (m == i) ? di : sE[m];
        arow[m] = __expf(sc - mx) * inv;
    }
}

// ---------------------------------------------------------------------------
// K3: i-independent output-GEMM factors. For row (b,j2) with
// h=j2>>6, j0=(j2&63)*2, j1=j0+1:
//   VW [b,j2,o] = bo[o] + sum_c V(j0,c)*Wo[c,o] + V(j1,c)*Wo[DK+c,o]
//   DW0[b,j2,o] = sum_c (BX(j0,c)-V(j0,c))*Wo[c,o]
//   DW1[b,j2,o] = sum_c (BX(j1,c)-V(j1,c))*Wo[DK+c,o]
// where V(j,c) = V[b,j, h*DK + c].  Grid: 64 blocks of 256 (8 cols/thread).
// ---------------------------------------------------------------------------
__global__ __launch_bounds__(256) void vwdw_kernel(
    const float* __restrict__ V, const float* __restrict__ BX,
    const float* __restrict__ Wo, const float* __restrict__ bo,
    float* __restrict__ VW, float* __restrict__ DW0, float* __restrict__ DW1)
{
    int gid = blockIdx.x * 256 + threadIdx.x;   // 0..16383
    int chunks = DMM >> 3;                      // 64
    int rowid = gid / chunks;                   // 0..255 = b*128 + j2
    int o0 = (gid % chunks) * 8;
    int b = rowid >> 7, j2 = rowid & 127;
    int h = j2 >> 6;
    int jj = (j2 & 63) * 2;                     // token index j0

    const float* v0 = V + (b * NN + jj) * DMM + h * DKK;
    const float* v1 = V + (b * NN + jj + 1) * DMM + h * DKK;
    const float* x0 = BX + (b * NN + jj) * DKK;
    const float* x1 = BX + (b * NN + jj + 1) * DKK;

    float avw[8], ad0[8], ad1[8];
#pragma unroll
    for (int j = 0; j < 8; j++) { avw[j] = bo[o0 + j]; ad0[j] = 0.f; ad1[j] = 0.f; }

    for (int c = 0; c < DKK; c++) {
        float v0c = v0[c], v1c = v1[c];
        float d0c = x0[c] - v0c, d1c = x1[c] - v1c;
        const float4 t0 = *(const float4*)(Wo + c * DMM + o0);
        const float4 t1 = *(const float4*)(Wo + c * DMM + o0 + 4);
        const float4 u0 = *(const float4*)(Wo + (DKK + c) * DMM + o0);
        const float4 u1 = *(const float4*)(Wo + (DKK + c) * DMM + o0 + 4);
        avw[0] += v0c * t0.x + v1c * u0.x; ad0[0] += d0c * t0.x; ad1[0] += d1c * u0.x;
        avw[1] += v0c * t0.y + v1c * u0.y; ad0[1] += d0c * t0.y; ad1[1] += d1c * u0.y;
        avw[2] += v0c * t0.z + v1c * u0.z; ad0[2] += d0c * t0.z; ad1[2] += d1c * u0.z;
        avw[3] += v0c * t0.w + v1c * u0.w; ad0[3] += d0c * t0.w; ad1[3] += d1c * u0.w;
        avw[4] += v0c * t1.x + v1c * u1.x; ad0[4] += d0c * t1.x; ad1[4] += d1c * u1.x;
        avw[5] += v0c * t1.y + v1c * u1.y; ad0[5] += d0c * t1.y; ad1[5] += d1c * u1.y;
        avw[6] += v0c * t1.z + v1c * u1.z; ad0[6] += d0c * t1.z; ad1[6] += d1c * u1.z;
        avw[7] += v0c * t1.w + v1c * u1.w; ad0[7] += d0c * t1.w; ad1[7] += d1c * u1.w;
    }
#pragma unroll
    for (int j = 0; j < 8; j++) {
        VW [rowid * DMM + o0 + j] = avw[j];
        DW0[rowid * DMM + o0 + j] = ad0[j];
        DW1[rowid * DMM + o0 + j] = ad1[j];
    }
}

// ---------------------------------------------------------------------------
// K4: output assembly (the big write, 67 MB fp32):
//   out[b,i,j2,o] = VW[b,j2,o] + attn[b,h,i,j0]*DW0[b,j2,o]
//                              + attn[b,h,i,j1]*DW1[b,j2,o]
// Grid: 256 blocks (b*128+j2) of 256 threads; thread owns 2 adjacent o,
// loops i, float2 stores.
// ---------------------------------------------------------------------------
__global__ __launch_bounds__(256) void out_kernel(
    const float* __restrict__ VW, const float* __restrict__ DW0,
    const float* __restrict__ DW1, const float* __restrict__ attn,
    float* __restrict__ out)
{
    int blk = blockIdx.x;            // b*128 + j2
    int b = blk >> 7, j2 = blk & 127;
    int h = j2 >> 6;
    int jj = (j2 & 63) * 2;
    int bh = b * HH + h;

    __shared__ float sa0[NN], sa1[NN];
    int tid = threadIdx.x;

    if (tid < NN) {
        sa0[tid] = attn[(bh * NN + tid) * NN + jj];
    } else {
        int i = tid - NN;
        sa1[i] = attn[(bh * NN + i) * NN + jj + 1];
    }
    __syncthreads();

    int o0 = tid * 2;
    float vw0 = VW [blk * DMM + o0], vw1 = VW [blk * DMM + o0 + 1];
    float d00 = DW0[blk * DMM + o0], d01 = DW0[blk * DMM + o0 + 1];
    float d10 = DW1[blk * DMM + o0], d11 = DW1[blk * DMM + o0 + 1];

    for (int i = 0; i < NN; i++) {
        float a0 = sa0[i], a1 = sa1[i];
        float2 r;
        r.x = vw0 + a0 * d00 + a1 * d10;
        r.y = vw1 + a0 * d01 + a1 * d11;
        *(float2*)(out + ((size_t)(b * NN + i) * NN + j2) * DMM + o0) = r;
    }
}

// ---------------------------------------------------------------------------
extern "C" void kernel_launch(void* const* d_in, const int* in_sizes, int n_in,
                              void* d_out, int out_size, void* d_ws, size_t ws_size,
                              hipStream_t stream)
{
    // Input-order detection (host-side, constant per session):
    // setup_inputs() dict order  -> in_sizes[1] == 131072 (key)
    // jax-pytree sorted order    -> in_sizes[1] == 262144 (Wk)
    const float *query, *key, *value, *boxes;
    const float *Wq, *bq, *Wk, *bk, *Wv, *bv, *Wb, *bb, *Wo, *bo;
    if (in_sizes[1] == 262144) {   // pytree-sorted order (not observed; fallback)
        Wb    = (const float*)d_in[0];
        Wk    = (const float*)d_in[1];
        Wo    = (const float*)d_in[2];
        Wq    = (const float*)d_in[3];
        Wv    = (const float*)d_in[4];
        bb    = (const float*)d_in[5];
        bk    = (const float*)d_in[6];
        bo    = (const float*)d_in[7];
        boxes = (const float*)d_in[8];
        bq    = (const float*)d_in[9];
        bv    = (const float*)d_in[10];
        key   = (const float*)d_in[11];
        query = (const float*)d_in[12];
        value = (const float*)d_in[13];
    } else {                        // setup_inputs() dict order (confirmed R2==R4)
        query = (const float*)d_in[0];
        key   = (const float*)d_in[1];
        value = (const float*)d_in[2];
        boxes = (const float*)d_in[3];
        Wq = (const float*)d_in[4];  bq = (const float*)d_in[5];
        Wk = (const float*)d_in[6];  bk = (const float*)d_in[7];
        Wv = (const float*)d_in[8];  bv = (const float*)d_in[9];
        Wb = (const float*)d_in[10]; bb = (const float*)d_in[11];
        Wo = (const float*)d_in[12]; bo = (const float*)d_in[13];
    }

    float* ws    = (float*)d_ws;
    float* Q     = ws;                  // 256*512
    float* K     = Q + 131072;          // 256*512
    float* V     = K + 131072;          // 256*512
    float* BX    = V + 131072;          // 256*256
    float* VW    = BX + 65536;          // 256*512
    float* DW0   = VW + 131072;         // 256*512
    float* DW1   = DW0 + 131072;        // 256*512

    float* out = (float*)d_out;                          // (2,128,128,512) fp32
    float* attn_out = out + (size_t)BB * NN * NN * DMM;  // (2,2,128,128) fp32

    proj_kernel<<<224, 256, 0, stream>>>(query, key, value, boxes,
                                         Wq, bq, Wk, bk, Wv, bv, Wb, bb,
                                         Q, K, V, BX);
    attn_kernel<<<4, 128, 0, stream>>>(Q, K, BX, attn_out);
    vwdw_kernel<<<64, 256, 0, stream>>>(V, BX, Wo, bo, VW, DW0, DW1);
    out_kernel<<<256, 256, 0, stream>>>(VW, DW0, DW1, attn_out, out);
}

// Round 6
// 228.193 us; speedup vs baseline: 1.3400x; 1.3400x over previous
//
#include <hip/hip_runtime.h>
#include <math.h>

// Problem constants (B, N, H, DM) = (2, 128, 2, 512), DK = 256
#define BB 2
#define NN 128
#define HH 2
#define DMM 512
#define DKK 256

typedef unsigned short u16;
typedef unsigned int u32;

// ---------------------------------------------------------------------------
// K1: fused projections (fp32 in, fp32 out to ws).
//   Q = query@Wq+bq, K = key@Wk+bk, V = value@Wv+bv   ((256,512)@(512,512))
//   BX = boxes@Wbox+bbox                              ((256,512)@(512,256))
// Thread computes 8 consecutive output cols; float4 loads for A and W.
// Grid: 64+64+64+32 = 224 blocks of 256.
// ---------------------------------------------------------------------------
__global__ __launch_bounds__(256) void proj_kernel(
    const float* __restrict__ q_in, const float* __restrict__ k_in,
    const float* __restrict__ v_in, const float* __restrict__ bx_in,
    const float* __restrict__ Wq, const float* __restrict__ bq,
    const float* __restrict__ Wk, const float* __restrict__ bk,
    const float* __restrict__ Wv, const float* __restrict__ bv,
    const float* __restrict__ Wb, const float* __restrict__ bb,
    float* __restrict__ Q, float* __restrict__ K,
    float* __restrict__ V, float* __restrict__ BX)
{
    int blk = blockIdx.x;
    const float *A, *W, *bias;
    float* out;
    int cols, base;
    if (blk < 64)       { A = q_in;  W = Wq; bias = bq; out = Q;  cols = 512; base = 0;   }
    else if (blk < 128) { A = k_in;  W = Wk; bias = bk; out = K;  cols = 512; base = 64;  }
    else if (blk < 192) { A = v_in;  W = Wv; bias = bv; out = V;  cols = 512; base = 128; }
    else                { A = bx_in; W = Wb; bias = bb; out = BX; cols = 256; base = 192; }

    int gid = (blk - base) * 256 + threadIdx.x;
    int chunks = cols >> 3;                 // chunks of 8 cols per row
    int row = gid / chunks;                 // 0..255
    int o0  = (gid % chunks) * 8;

    const float4* a4 = (const float4*)(A + row * DMM);
    float acc[8];
#pragma unroll
    for (int j = 0; j < 8; j++) acc[j] = bias[o0 + j];

#pragma unroll 2
    for (int k4 = 0; k4 < DMM / 4; k4++) {
        float4 av = a4[k4];
        int kk = k4 * 4;
#pragma unroll
        for (int s = 0; s < 4; s++) {
            float a = (s == 0) ? av.x : (s == 1) ? av.y : (s == 2) ? av.z : av.w;
            const float4 w0 = *(const float4*)(W + (kk + s) * cols + o0);
            const float4 w1 = *(const float4*)(W + (kk + s) * cols + o0 + 4);
            acc[0] += a * w0.x; acc[1] += a * w0.y;
            acc[2] += a * w0.z; acc[3] += a * w0.w;
            acc[4] += a * w1.x; acc[5] += a * w1.y;
            acc[6] += a * w1.z; acc[7] += a * w1.w;
        }
    }
    float* orow = out + row * cols + o0;
#pragma unroll
    for (int j = 0; j < 8; j++) orow[j] = acc[j];
}

// ---------------------------------------------------------------------------
// K2: per-(b,h) stats + softmax.
// Row-i scores (after dropping the row-constant softmax shift) are:
//   m != i :  e_m = scale*(c_m - t_m)
//   m == i :  d_i = scale*(g_i - a_i)
// with t=q.k, a=bx.k, c=q.bx, g=bx.bx over DK.
// attn written fp32 directly into d_out's second output region; K4 re-reads.
// Grid: 4 blocks (b*H+h) of 128 threads.
// ---------------------------------------------------------------------------
__global__ __launch_bounds__(128) void attn_kernel(
    const float* __restrict__ Q, const float* __restrict__ K,
    const float* __restrict__ BX,
    float* __restrict__ attn_out)
{
    int bh = blockIdx.x;          // 0..3
    int b = bh >> 1, h = bh & 1;
    __shared__ float sE[NN], sD[NN];
    int tid = threadIdx.x;        // 0..127

    {   // phase 1: per-token dots (float4 vectorized)
        int j = tid;
        const float4* qp = (const float4*)(Q + (b * NN + j) * DMM + h * DKK);
        const float4* kp = (const float4*)(K + (b * NN + j) * DMM + h * DKK);
        const float4* xp = (const float4*)(BX + (b * NN + j) * DKK);
        float t = 0.f, a = 0.f, c = 0.f, g = 0.f;
#pragma unroll 4
        for (int ci = 0; ci < DKK / 4; ci++) {
            float4 qv = qp[ci], kv = kp[ci], xv = xp[ci];
            t += qv.x * kv.x + qv.y * kv.y + qv.z * kv.z + qv.w * kv.w;
            a += xv.x * kv.x + xv.y * kv.y + xv.z * kv.z + xv.w * kv.w;
            c += qv.x * xv.x + qv.y * xv.y + qv.z * xv.z + qv.w * xv.w;
            g += xv.x * xv.x + xv.y * xv.y + xv.z * xv.z + xv.w * xv.w;
        }
        const float scale = 1.0f / sqrtf((float)(NN * DKK));
        sE[j] = scale * (c - t);
        sD[j] = scale * (g - a);
    }
    __syncthreads();

    // phase 2: one softmax row per thread
    int i = tid;
    float di = sD[i];
    float mx = di;
    for (int m = 0; m < NN; m++) {
        float sc = (m == i) ? di : sE[m];
        mx = fmaxf(mx, sc);
    }
    float sum = 0.f;
    for (int m = 0; m < NN; m++) {
        float sc = (m == i) ? di : sE[m];
        sum += __expf(sc - mx);
    }
    float inv = 1.0f / sum;
    float* arow = attn_out + (bh * NN + i) * NN;
    for (int m = 0; m < NN; m++) {
        float sc = (m == i) ? di : sE[m];
        arow[m] = __expf(sc - mx) * inv;
    }
}

// ---------------------------------------------------------------------------
// K3 (fused vwdw+out): one block per (b,j2).
// Phase A (registers, Wo streamed from L2, V/BX rows broadcast from LDS):
//   avw[o] = bo[o] + sum_c V(j0,c)*Wo[c,o] + V(j1,c)*Wo[DK+c,o]
//   a0 [o] = sum_c (BX(j0,c)-V(j0,c))*Wo[c,o]
//   a1 [o] = sum_c (BX(j1,c)-V(j1,c))*Wo[DK+c,o]
// Phase B (the big 67 MB write):
//   out[b,i,j2,o] = avw[o] + attn[b,h,i,j0]*a0[o] + attn[b,h,i,j1]*a1[o]
// Grid: 256 blocks of 256 threads; thread owns 2 adjacent o.
// ---------------------------------------------------------------------------
__global__ __launch_bounds__(256) void fused_out_kernel(
    const float* __restrict__ V, const float* __restrict__ BX,
    const float* __restrict__ Wo, const float* __restrict__ bo,
    const float* __restrict__ attn, float* __restrict__ out)
{
    int blk = blockIdx.x;            // b*128 + j2
    int b = blk >> 7, j2 = blk & 127;
    int h = j2 >> 6;
    int jj = (j2 & 63) * 2;          // token j0 ; j1 = jj+1
    int bh = b * HH + h;
    int tid = threadIdx.x;

    __shared__ float sv0[DKK], sv1[DKK], sx0[DKK], sx1[DKK];
    __shared__ float sa0[NN], sa1[NN];

    {   // stage V/BX rows (1 elem per thread per array; coalesced)
        const float* v0 = V  + (b * NN + jj)     * DMM + h * DKK;
        const float* v1 = V  + (b * NN + jj + 1) * DMM + h * DKK;
        const float* x0 = BX + (b * NN + jj)     * DKK;
        const float* x1 = BX + (b * NN + jj + 1) * DKK;
        sv0[tid] = v0[tid];
        sv1[tid] = v1[tid];
        sx0[tid] = x0[tid];
        sx1[tid] = x1[tid];
        // stage attn columns j0, j1 for all i
        if (tid < NN) sa0[tid] = attn[(bh * NN + tid) * NN + jj];
        else          sa1[tid - NN] = attn[(bh * NN + (tid - NN)) * NN + jj + 1];
    }
    __syncthreads();

    int o0 = tid * 2;
    float2 bo2 = *(const float2*)(bo + o0);
    float avw0 = bo2.x, avw1 = bo2.y;
    float a00 = 0.f, a01 = 0.f, a10 = 0.f, a11 = 0.f;

#pragma unroll 4
    for (int c = 0; c < DKK; c++) {
        float2 wt = *(const float2*)(Wo + c * DMM + o0);           // top row
        float2 wb = *(const float2*)(Wo + (DKK + c) * DMM + o0);   // bottom row
        float v0c = sv0[c], v1c = sv1[c];
        float d0c = sx0[c] - v0c, d1c = sx1[c] - v1c;
        avw0 += v0c * wt.x + v1c * wb.x;
        avw1 += v0c * wt.y + v1c * wb.y;
        a00 += d0c * wt.x; a01 += d0c * wt.y;
        a10 += d1c * wb.x; a11 += d1c * wb.y;
    }

    for (int i = 0; i < NN; i++) {
        float p0 = sa0[i], p1 = sa1[i];
        float2 r;
        r.x = avw0 + p0 * a00 + p1 * a10;
        r.y = avw1 + p0 * a01 + p1 * a11;
        *(float2*)(out + ((size_t)(b * NN + i) * NN + j2) * DMM + o0) = r;
    }
}

// ---------------------------------------------------------------------------
extern "C" void kernel_launch(void* const* d_in, const int* in_sizes, int n_in,
                              void* d_out, int out_size, void* d_ws, size_t ws_size,
                              hipStream_t stream)
{
    // Input-order detection (host-side, constant per session):
    // setup_inputs() dict order  -> in_sizes[1] == 131072 (key)   [confirmed]
    // jax-pytree sorted order    -> in_sizes[1] == 262144 (Wk)    [fallback]
    const float *query, *key, *value, *boxes;
    const float *Wq, *bq, *Wk, *bk, *Wv, *bv, *Wb, *bb, *Wo, *bo;
    if (in_sizes[1] == 262144) {
        Wb    = (const float*)d_in[0];
        Wk    = (const float*)d_in[1];
        Wo    = (const float*)d_in[2];
        Wq    = (const float*)d_in[3];
        Wv    = (const float*)d_in[4];
        bb    = (const float*)d_in[5];
        bk    = (const float*)d_in[6];
        bo    = (const float*)d_in[7];
        boxes = (const float*)d_in[8];
        bq    = (const float*)d_in[9];
        bv    = (const float*)d_in[10];
        key   = (const float*)d_in[11];
        query = (const float*)d_in[12];
        value = (const float*)d_in[13];
    } else {
        query = (const float*)d_in[0];
        key   = (const float*)d_in[1];
        value = (const float*)d_in[2];
        boxes = (const float*)d_in[3];
        Wq = (const float*)d_in[4];  bq = (const float*)d_in[5];
        Wk = (const float*)d_in[6];  bk = (const float*)d_in[7];
        Wv = (const float*)d_in[8];  bv = (const float*)d_in[9];
        Wb = (const float*)d_in[10]; bb = (const float*)d_in[11];
        Wo = (const float*)d_in[12]; bo = (const float*)d_in[13];
    }

    float* ws    = (float*)d_ws;
    float* Q     = ws;                  // 256*512
    float* K     = Q + 131072;          // 256*512
    float* V     = K + 131072;          // 256*512
    float* BX    = V + 131072;          // 256*256

    float* out = (float*)d_out;                          // (2,128,128,512) fp32
    float* attn_out = out + (size_t)BB * NN * NN * DMM;  // (2,2,128,128) fp32

    proj_kernel<<<224, 256, 0, stream>>>(query, key, value, boxes,
                                         Wq, bq, Wk, bk, Wv, bv, Wb, bb,
                                         Q, K, V, BX);
    attn_kernel<<<4, 128, 0, stream>>>(Q, K, BX, attn_out);
    fused_out_kernel<<<256, 256, 0, stream>>>(V, BX, Wo, bo, attn_out, out);
}

// Round 7
// 197.260 us; speedup vs baseline: 1.5502x; 1.1568x over previous
//
#include <hip/hip_runtime.h>
#include <math.h>

// Problem constants (B, N, H, DM) = (2, 128, 2, 512), DK = 256
#define BB 2
#define NN 128
#define HH 2
#define DMM 512
#define DKK 256

typedef unsigned short u16;
typedef unsigned int u32;

// Partial-output layout inside each of P0/P1 (floats):
//   Q at 0, K at 131072, V at 262144, BX at 393216, total 458752
#define POFF_Q  0
#define POFF_K  131072
#define POFF_V  262144
#define POFF_BX 393216
#define PSIZE   458752

// ---------------------------------------------------------------------------
// K1: tiled projections with split-K=2.
// Computes partial sums over k-half kh into P[kh]:
//   P[kh]{Q,K,V,BX}[row, n] = (kh==0 ? bias[n] : 0) + sum_{k in half} A[row,k]*W[k,n]
// Tile: 32 rows x 128 cols, TK=64; thread = 4x4 register tile.
// Grid: 224 blocks (= 2 k-halves x 112 tiles) x 256 threads.
// LDS: sA transposed (+1 pad), sW natural. 40.25 KB.
// ---------------------------------------------------------------------------
__global__ __launch_bounds__(256) void proj_kernel(
    const float* __restrict__ q_in, const float* __restrict__ k_in,
    const float* __restrict__ v_in, const float* __restrict__ bx_in,
    const float* __restrict__ Wq, const float* __restrict__ bq,
    const float* __restrict__ Wk, const float* __restrict__ bk,
    const float* __restrict__ Wv, const float* __restrict__ bv,
    const float* __restrict__ Wb, const float* __restrict__ bb,
    float* __restrict__ P0, float* __restrict__ P1)
{
    int id = blockIdx.x;
    int kh   = id & 1;            // k-half
    int tile = id >> 1;           // 0..111

    const float *A, *W, *bias;
    int cols, local, off;
    if (tile < 32)      { A = q_in;  W = Wq; bias = bq; cols = 512; local = tile;      off = POFF_Q;  }
    else if (tile < 64) { A = k_in;  W = Wk; bias = bk; cols = 512; local = tile - 32; off = POFF_K;  }
    else if (tile < 96) { A = v_in;  W = Wv; bias = bv; cols = 512; local = tile - 64; off = POFF_V;  }
    else                { A = bx_in; W = Wb; bias = bb; cols = 256; local = tile - 96; off = POFF_BX; }

    int ntiles = cols >> 7;                  // 4 or 2 N-tiles
    int mt = local / ntiles, nt = local % ntiles;
    int row0 = mt * 32, n0 = nt * 128;
    float* outp = (kh ? P1 : P0) + off;
    int k0base = kh * 256;

    __shared__ float sA[64][33];             // [k][row], padded
    __shared__ float sW[64][128];            // [k][col]

    int tid = threadIdx.x;
    int rg = tid >> 5;                       // 0..7  -> rows 4*rg..+3
    int cg = tid & 31;                       // 0..31 -> cols 4*cg..+3

    float acc[4][4];
    if (kh == 0) {
        float4 bv4 = *(const float4*)(bias + n0 + 4 * cg);
#pragma unroll
        for (int r = 0; r < 4; r++) {
            acc[r][0] = bv4.x; acc[r][1] = bv4.y; acc[r][2] = bv4.z; acc[r][3] = bv4.w;
        }
    } else {
#pragma unroll
        for (int r = 0; r < 4; r++)
#pragma unroll
            for (int c = 0; c < 4; c++) acc[r][c] = 0.f;
    }

    for (int kc = 0; kc < 4; kc++) {
        int k0 = k0base + kc * 64;
        // stage A-tile (32 rows x 64 k) transposed into sA
#pragma unroll
        for (int s = 0; s < 2; s++) {
            int idx = tid + s * 256;         // 0..511
            int r = idx >> 4;                // 0..31
            int f4 = (idx & 15) * 4;         // 0..60
            float4 v = *(const float4*)(A + (row0 + r) * DMM + k0 + f4);
            sA[f4 + 0][r] = v.x; sA[f4 + 1][r] = v.y;
            sA[f4 + 2][r] = v.z; sA[f4 + 3][r] = v.w;
        }
        // stage W-tile (64 k x 128 cols)
#pragma unroll
        for (int s = 0; s < 8; s++) {
            int idx = tid + s * 256;         // 0..2047
            int kk = idx >> 5;               // 0..63
            int c4 = (idx & 31) * 4;         // 0..124
            *(float4*)&sW[kk][c4] = *(const float4*)(W + (k0 + kk) * cols + n0 + c4);
        }
        __syncthreads();

#pragma unroll 8
        for (int kk = 0; kk < 64; kk++) {
            float4 a4 = *(float4*)&sA[kk][4 * rg];
            float4 w4 = *(float4*)&sW[kk][4 * cg];
            acc[0][0] += a4.x * w4.x; acc[0][1] += a4.x * w4.y; acc[0][2] += a4.x * w4.z; acc[0][3] += a4.x * w4.w;
            acc[1][0] += a4.y * w4.x; acc[1][1] += a4.y * w4.y; acc[1][2] += a4.y * w4.z; acc[1][3] += a4.y * w4.w;
            acc[2][0] += a4.z * w4.x; acc[2][1] += a4.z * w4.y; acc[2][2] += a4.z * w4.z; acc[2][3] += a4.z * w4.w;
            acc[3][0] += a4.w * w4.x; acc[3][1] += a4.w * w4.y; acc[3][2] += a4.w * w4.z; acc[3][3] += a4.w * w4.w;
        }
        __syncthreads();
    }

#pragma unroll
    for (int r = 0; r < 4; r++) {
        float4 v; v.x = acc[r][0]; v.y = acc[r][1]; v.z = acc[r][2]; v.w = acc[r][3];
        *(float4*)(outp + (row0 + 4 * rg + r) * cols + n0 + 4 * cg) = v;
    }
}

// ---------------------------------------------------------------------------
// K2: per-(b,h) stats + softmax.  Reads Q/K/BX as P0+P1 partial sums.
// Row-i scores (after dropping the row-constant softmax shift):
//   m != i :  e_m = scale*(c_m - t_m)
//   m == i :  d_i = scale*(g_i - a_i)
// with t=q.k, a=bx.k, c=q.bx, g=bx.bx over DK.
// attn written fp32 directly into d_out's second output region.
// Grid: 4 blocks (b*H+h) of 128 threads.
// ---------------------------------------------------------------------------
__global__ __launch_bounds__(128) void attn_kernel(
    const float* __restrict__ P0, const float* __restrict__ P1,
    float* __restrict__ attn_out)
{
    int bh = blockIdx.x;          // 0..3
    int b = bh >> 1, h = bh & 1;
    __shared__ float sE[NN], sD[NN];
    int tid = threadIdx.x;        // 0..127

    {   // phase 1: per-token dots (float4, summing the two k-half partials)
        int j = tid;
        size_t qoff = (size_t)POFF_Q  + (b * NN + j) * DMM + h * DKK;
        size_t koff = (size_t)POFF_K  + (b * NN + j) * DMM + h * DKK;
        size_t xoff = (size_t)POFF_BX + (b * NN + j) * DKK;
        const float4* q0 = (const float4*)(P0 + qoff);
        const float4* q1 = (const float4*)(P1 + qoff);
        const float4* k0 = (const float4*)(P0 + koff);
        const float4* k1 = (const float4*)(P1 + koff);
        const float4* x0 = (const float4*)(P0 + xoff);
        const float4* x1 = (const float4*)(P1 + xoff);
        float t = 0.f, a = 0.f, c = 0.f, g = 0.f;
#pragma unroll 4
        for (int ci = 0; ci < DKK / 4; ci++) {
            float4 qa = q0[ci], qb = q1[ci];
            float4 ka = k0[ci], kb = k1[ci];
            float4 xa = x0[ci], xb = x1[ci];
            float4 qv, kv, xv;
            qv.x = qa.x + qb.x; qv.y = qa.y + qb.y; qv.z = qa.z + qb.z; qv.w = qa.w + qb.w;
            kv.x = ka.x + kb.x; kv.y = ka.y + kb.y; kv.z = ka.z + kb.z; kv.w = ka.w + kb.w;
            xv.x = xa.x + xb.x; xv.y = xa.y + xb.y; xv.z = xa.z + xb.z; xv.w = xa.w + xb.w;
            t += qv.x * kv.x + qv.y * kv.y + qv.z * kv.z + qv.w * kv.w;
            a += xv.x * kv.x + xv.y * kv.y + xv.z * kv.z + xv.w * kv.w;
            c += qv.x * xv.x + qv.y * xv.y + qv.z * xv.z + qv.w * xv.w;
            g += xv.x * xv.x + xv.y * xv.y + xv.z * xv.z + xv.w * xv.w;
        }
        const float scale = 1.0f / sqrtf((float)(NN * DKK));
        sE[j] = scale * (c - t);
        sD[j] = scale * (g - a);
    }
    __syncthreads();

    // phase 2: one softmax row per thread
    int i = tid;
    float di = sD[i];
    float mx = di;
    for (int m = 0; m < NN; m++) {
        float sc = (m == i) ? di : sE[m];
        mx = fmaxf(mx, sc);
    }
    float sum = 0.f;
    for (int m = 0; m < NN; m++) {
        float sc = (m == i) ? di : sE[m];
        sum += __expf(sc - mx);
    }
    float inv = 1.0f / sum;
    float* arow = attn_out + (bh * NN + i) * NN;
    for (int m = 0; m < NN; m++) {
        float sc = (m == i) ? di : sE[m];
        arow[m] = __expf(sc - mx) * inv;
    }
}

// ---------------------------------------------------------------------------
// K3 (fused vwdw+out): one block per (b,j2).  V/BX staged as P0+P1 sums.
// Phase A (registers, Wo streamed from L2, V/BX rows broadcast from LDS):
//   avw[o] = bo[o] + sum_c V(j0,c)*Wo[c,o] + V(j1,c)*Wo[DK+c,o]
//   a0 [o] = sum_c (BX(j0,c)-V(j0,c))*Wo[c,o]
//   a1 [o] = sum_c (BX(j1,c)-V(j1,c))*Wo[DK+c,o]
// Phase B (the big 67 MB write):
//   out[b,i,j2,o] = avw[o] + attn[b,h,i,j0]*a0[o] + attn[b,h,i,j1]*a1[o]
// Grid: 256 blocks of 256 threads; thread owns 2 adjacent o.
// ---------------------------------------------------------------------------
__global__ __launch_bounds__(256) void fused_out_kernel(
    const float* __restrict__ P0, const float* __restrict__ P1,
    const float* __restrict__ Wo, const float* __restrict__ bo,
    const float* __restrict__ attn, float* __restrict__ out)
{
    int blk = blockIdx.x;            // b*128 + j2
    int b = blk >> 7, j2 = blk & 127;
    int h = j2 >> 6;
    int jj = (j2 & 63) * 2;          // token j0 ; j1 = jj+1
    int bh = b * HH + h;
    int tid = threadIdx.x;

    __shared__ float sv0[DKK], sv1[DKK], sx0[DKK], sx1[DKK];
    __shared__ float sa0[NN], sa1[NN];

    {
        size_t v0o = (size_t)POFF_V  + (b * NN + jj)     * DMM + h * DKK + tid;
        size_t v1o = (size_t)POFF_V  + (b * NN + jj + 1) * DMM + h * DKK + tid;
        size_t x0o = (size_t)POFF_BX + (b * NN + jj)     * DKK + tid;
        size_t x1o = (size_t)POFF_BX + (b * NN + jj + 1) * DKK + tid;
        sv0[tid] = P0[v0o] + P1[v0o];
        sv1[tid] = P0[v1o] + P1[v1o];
        sx0[tid] = P0[x0o] + P1[x0o];
        sx1[tid] = P0[x1o] + P1[x1o];
        if (tid < NN) sa0[tid] = attn[(bh * NN + tid) * NN + jj];
        else          sa1[tid - NN] = attn[(bh * NN + (tid - NN)) * NN + jj + 1];
    }
    __syncthreads();

    int o0 = tid * 2;
    float2 bo2 = *(const float2*)(bo + o0);
    float avw0 = bo2.x, avw1 = bo2.y;
    float a00 = 0.f, a01 = 0.f, a10 = 0.f, a11 = 0.f;

#pragma unroll 4
    for (int c = 0; c < DKK; c++) {
        float2 wt = *(const float2*)(Wo + c * DMM + o0);           // top row
        float2 wb = *(const float2*)(Wo + (DKK + c) * DMM + o0);   // bottom row
        float v0c = sv0[c], v1c = sv1[c];
        float d0c = sx0[c] - v0c, d1c = sx1[c] - v1c;
        avw0 += v0c * wt.x + v1c * wb.x;
        avw1 += v0c * wt.y + v1c * wb.y;
        a00 += d0c * wt.x; a01 += d0c * wt.y;
        a10 += d1c * wb.x; a11 += d1c * wb.y;
    }

    for (int i = 0; i < NN; i++) {
        float p0 = sa0[i], p1 = sa1[i];
        float2 r;
        r.x = avw0 + p0 * a00 + p1 * a10;
        r.y = avw1 + p0 * a01 + p1 * a11;
        *(float2*)(out + ((size_t)(b * NN + i) * NN + j2) * DMM + o0) = r;
    }
}

// ---------------------------------------------------------------------------
extern "C" void kernel_launch(void* const* d_in, const int* in_sizes, int n_in,
                              void* d_out, int out_size, void* d_ws, size_t ws_size,
                              hipStream_t stream)
{
    // Input-order detection (host-side, constant per session):
    // setup_inputs() dict order  -> in_sizes[1] == 131072 (key)   [confirmed]
    // jax-pytree sorted order    -> in_sizes[1] == 262144 (Wk)    [fallback]
    const float *query, *key, *value, *boxes;
    const float *Wq, *bq, *Wk, *bk, *Wv, *bv, *Wb, *bb, *Wo, *bo;
    if (in_sizes[1] == 262144) {
        Wb    = (const float*)d_in[0];
        Wk    = (const float*)d_in[1];
        Wo    = (const float*)d_in[2];
        Wq    = (const float*)d_in[3];
        Wv    = (const float*)d_in[4];
        bb    = (const float*)d_in[5];
        bk    = (const float*)d_in[6];
        bo    = (const float*)d_in[7];
        boxes = (const float*)d_in[8];
        bq    = (const float*)d_in[9];
        bv    = (const float*)d_in[10];
        key   = (const float*)d_in[11];
        query = (const float*)d_in[12];
        value = (const float*)d_in[13];
    } else {
        query = (const float*)d_in[0];
        key   = (const float*)d_in[1];
        value = (const float*)d_in[2];
        boxes = (const float*)d_in[3];
        Wq = (const float*)d_in[4];  bq = (const float*)d_in[5];
        Wk = (const float*)d_in[6];  bk = (const float*)d_in[7];
        Wv = (const float*)d_in[8];  bv = (const float*)d_in[9];
        Wb = (const float*)d_in[10]; bb = (const float*)d_in[11];
        Wo = (const float*)d_in[12]; bo = (const float*)d_in[13];
    }

    float* ws = (float*)d_ws;
    float* P0 = ws;                 // partial sums, k-half 0 (incl. bias)
    float* P1 = ws + PSIZE;         // partial sums, k-half 1

    float* out = (float*)d_out;                          // (2,128,128,512) fp32
    float* attn_out = out + (size_t)BB * NN * NN * DMM;  // (2,2,128,128) fp32

    proj_kernel<<<224, 256, 0, stream>>>(query, key, value, boxes,
                                         Wq, bq, Wk, bk, Wv, bv, Wb, bb,
                                         P0, P1);
    attn_kernel<<<4, 128, 0, stream>>>(P0, P1, attn_out);
    fused_out_kernel<<<256, 256, 0, stream>>>(P0, P1, Wo, bo, attn_out, out);
}